// Round 5
// baseline (750.100 us; speedup 1.0000x reference)
//
#include <hip/hip_runtime.h>
#include <hip/hip_bf16.h>
#include <cstdint>

// ---------------------------------------------------------------------------
// LSTM cell fused forward on MI355X (gfx950).
//   gates = [input|hidden] @ [W;U] + b   (fp32 via 3-product bf16 MFMA emulation)
//   gate GEMM: 256x256 tile, 32x32x16 MFMA, FRAGMENT-LINEAR panel layout
//              (conflict-free LDS, coalesced staging), 2 phases/K-tile,
//              counted vmcnt(6)
//   elementwise LSTM epilogue fused into gate GEMM
//   logits = h_new @ W_h + b_h           (128^2 bf16x3 GEMM)
//   log_softmax row-wise
// ---------------------------------------------------------------------------

#define B_DIM   8192
#define K1      2048   // IN + H
#define H_DIM   1024

typedef __attribute__((ext_vector_type(8)))  __bf16 bf16x8;
typedef __attribute__((ext_vector_type(4)))  float  f32x4;
typedef __attribute__((ext_vector_type(16))) float  f32x16;

__device__ __forceinline__ unsigned short f2bf(float f) {
    unsigned int u = __float_as_uint(f);
    u += 0x7FFFu + ((u >> 16) & 1u);
    return (unsigned short)(u >> 16);
}
__device__ __forceinline__ float bf2f(unsigned short s) {
    return __uint_as_float(((unsigned int)s) << 16);
}

__device__ __forceinline__ void gload_lds16(const void* g, void* l) {
    __builtin_amdgcn_global_load_lds(
        (const __attribute__((address_space(1))) void*)g,
        (__attribute__((address_space(3))) void*)l, 16, 0, 0);
}

__device__ __forceinline__ unsigned lds_off(const void* p) {
    return (unsigned)(uintptr_t)(const __attribute__((address_space(3))) void*)p;
}

__device__ __forceinline__ bf16x8 dsr128(unsigned addr) {
    bf16x8 r;
    asm volatile("ds_read_b128 %0, %1" : "=v"(r) : "v"(addr));
    return r;
}

__device__ __forceinline__ f32x4 mfma16(bf16x8 a, bf16x8 b, f32x4 c) {
    return __builtin_amdgcn_mfma_f32_16x16x32_bf16(a, b, c, 0, 0, 0);
}
__device__ __forceinline__ f32x16 mfma32(bf16x8 a, bf16x8 b, f32x16 c) {
    return __builtin_amdgcn_mfma_f32_32x32x16_bf16(a, b, c, 0, 0, 0);
}

// Panel-layout byte address for element (r, k) of a [R][2048] matrix, hi/lo part:
//   panel = r>>8, g = (r>>5)&7, l31 = r&31, t = k>>5, kk = (k>>4)&1,
//   lh = (k>>3)&1, j = k&7
//   byte = ((panel*64 + t)*32 + g*4 + kk*2 + part)*1024 + (lh*32+l31)*16 + j*2
__device__ __forceinline__ int64_t pan_addr(int r, int k, int part) {
    int panel = r >> 8, g = (r >> 5) & 7, l31 = r & 31;
    int t = k >> 5, kk = (k >> 4) & 1, lh = (k >> 3) & 1, j = k & 7;
    return ((int64_t)((panel * 64 + t) * 32 + g * 4 + kk * 2 + part)) * 1024
           + (lh * 32 + l31) * 16 + j * 2;
}

// ---------------------------------------------------------------------------
// Pack X = [input | hidden] into panel layout (hi/lo interleaved as part).
// ---------------------------------------------------------------------------
__global__ __launch_bounds__(256) void k_pack_x(
    const float* __restrict__ input, const float* __restrict__ hidden,
    char* __restrict__ Apan) {
    const int64_t n4 = (int64_t)B_DIM * K1 / 4;
    for (int64_t i = (int64_t)blockIdx.x * blockDim.x + threadIdx.x; i < n4;
         i += (int64_t)gridDim.x * blockDim.x) {
        int64_t e = i * 4;
        int row = (int)(e >> 11);
        int col = (int)(e & 2047);
        const float* src = (col < 1024) ? (input + (int64_t)row * 1024 + col)
                                        : (hidden + (int64_t)row * 1024 + (col - 1024));
        float4 v = *(const float4*)src;
        ushort4 hv, lv;
        hv.x = f2bf(v.x); lv.x = f2bf(v.x - bf2f(hv.x));
        hv.y = f2bf(v.y); lv.y = f2bf(v.y - bf2f(hv.y));
        hv.z = f2bf(v.z); lv.z = f2bf(v.z - bf2f(hv.z));
        hv.w = f2bf(v.w); lv.w = f2bf(v.w - bf2f(hv.w));
        int64_t a = pan_addr(row, col, 0);   // col%8 in {0,4}: 8B-aligned
        *(ushort4*)(Apan + a) = hv;
        *(ushort4*)(Apan + a + 1024) = lv;
    }
}

// ---------------------------------------------------------------------------
// Transpose+split W/U [1024x1024] (k-major) into Bpan panel layout at
// n' = h*4 + ng, k = koff + klocal.
// ---------------------------------------------------------------------------
__global__ __launch_bounds__(256) void k_trans_split_pan(
    const float* __restrict__ src, char* __restrict__ Bpan, int ng, int koff) {
    __shared__ float tt[64][65];
    const int h0 = blockIdx.x * 64;
    const int k0 = blockIdx.y * 64;
    const int tx = threadIdx.x & 63, ty = threadIdx.x >> 6;
    #pragma unroll
    for (int r = ty; r < 64; r += 4)
        tt[r][tx] = src[(int64_t)(k0 + r) * 1024 + h0 + tx];
    __syncthreads();
    #pragma unroll
    for (int r = ty; r < 64; r += 4) {
        float v = tt[tx][r];               // element (k = k0+tx, h = h0+r)
        unsigned short hi = f2bf(v);
        unsigned short lo = f2bf(v - bf2f(hi));
        int np = (h0 + r) * 4 + ng;
        int kk = koff + k0 + tx;
        int64_t a = pan_addr(np, kk, 0);
        *(unsigned short*)(Bpan + a) = hi;
        *(unsigned short*)(Bpan + a + 1024) = lo;
    }
}

// Old-layout transpose+split for W_h (row-major [n][k] hi/lo arrays).
__global__ __launch_bounds__(256) void k_trans_split(
    const float* __restrict__ src,
    unsigned short* __restrict__ dhi, unsigned short* __restrict__ dlo) {
    __shared__ float tt[64][65];
    const int h0 = blockIdx.x * 64;
    const int k0 = blockIdx.y * 64;
    const int tx = threadIdx.x & 63, ty = threadIdx.x >> 6;
    #pragma unroll
    for (int r = ty; r < 64; r += 4)
        tt[r][tx] = src[(int64_t)(k0 + r) * 1024 + h0 + tx];
    __syncthreads();
    #pragma unroll
    for (int r = ty; r < 64; r += 4) {
        float v = tt[tx][r];
        unsigned short hi = f2bf(v);
        unsigned short lo = f2bf(v - bf2f(hi));
        int64_t o = (int64_t)(h0 + r) * 1024 + k0 + tx;
        dhi[o] = hi;
        dlo[o] = lo;
    }
}

// bias4[n'] = b_g[h], n' = 4h+g
__global__ __launch_bounds__(256) void k_pack_bias(
    const float* __restrict__ bf_, const float* __restrict__ bi_,
    const float* __restrict__ bc_, const float* __restrict__ bo_,
    float* __restrict__ bias4) {
    int n = blockIdx.x * 256 + threadIdx.x;
    if (n < 4096) {
        int g = n & 3, h = n >> 2;
        const float* p = (g == 0) ? bf_ : (g == 1) ? bi_ : (g == 2) ? bc_ : bo_;
        bias4[n] = p[h];
    }
}

// ---------------------------------------------------------------------------
// GATE GEMM: bf16x3, 256x256 tile, BK=32, 8 waves (2M x 4N), 32x32x16 MFMA.
// Panel/fragment-linear LDS: buf c at c*64KB = A blocks 0..31 (1KB each,
// block = g*4+kk*2+part) then B blocks 0..31 (+32KB).  All ds_reads are
// lane*16-contiguous (conflict-free); staging is 8 wave-linear 8KB calls.
// 2 phases per K-tile; counted vmcnt(6); dep-distance-4 MFMA round-robin.
// ---------------------------------------------------------------------------
#define NT (K1 / 32)  // 64 K-tiles

__global__ __launch_bounds__(512, 2) void k_gate_gemm256(
    const char* __restrict__ Apan, const char* __restrict__ Bpan,
    const float* __restrict__ bias,
    const float* __restrict__ cell,
    float* __restrict__ out0,
    unsigned short* __restrict__ hhi, unsigned short* __restrict__ hlo) {
    extern __shared__ char smem[];  // 131072

    const int tid  = threadIdx.x;
    const int lane = tid & 63;
    const int w    = tid >> 6;             // wave 0..7
    const int l31  = lane & 31;
    const int lh   = lane >> 5;

    // XCD-aware swizzle: 512 blocks, 512%8==0
    const int bid = blockIdx.x;
    const int swz = (bid & 7) * 64 + (bid >> 3);
    const int panelA = swz >> 4;           // 32 m-panels
    const int panelB = swz & 15;           // 16 n-panels
    const int m0 = panelA * 256;
    const int n0 = panelB * 256;
    const int wr = (w >> 2) * 128;
    const int wc = (w & 3) * 64;

    f32x16 acc[4][2];
    #pragma unroll
    for (int i = 0; i < 4; i++)
        #pragma unroll
        for (int j = 0; j < 2; j++) acc[i][j] = (f32x16)(0.0f);

    // staging pointers: one 1KB block per wave per call, fully linear
    const char* srcA = Apan + ((int64_t)panelA << 21) + w * 1024 + lane * 16;
    const char* srcB = Bpan + ((int64_t)panelB << 21) + w * 1024 + lane * 16;

    auto STAGE_A = [&](int buf, int call, int t) {
        gload_lds16(srcA + (int64_t)t * 32768 + call * 8192,
                    smem + buf * 65536 + call * 8192 + w * 1024);
    };
    auto STAGE_B = [&](int buf, int call, int t) {
        gload_lds16(srcB + (int64_t)t * 32768 + call * 8192,
                    smem + buf * 65536 + 32768 + call * 8192 + w * 1024);
    };

    // ds_read bases (per-wave): offsets are (mf*4 + kk*2 + part)*1024
    const unsigned ldsBase = lds_off(smem);
    const unsigned aB = ldsBase + (unsigned)(((w >> 2) * 4) * 4096) + (unsigned)(lane * 16);
    const unsigned bB = ldsBase + 32768u + (unsigned)(((w & 3) * 2) * 4096) + (unsigned)(lane * 16);

    // ---- prologue: tile0 fully (8 calls); tile1 B + A calls 0,2 (6 calls) ----
    STAGE_A(0, 0, 0); STAGE_A(0, 1, 0); STAGE_A(0, 2, 0); STAGE_A(0, 3, 0);
    STAGE_B(0, 0, 0); STAGE_B(0, 1, 0); STAGE_B(0, 2, 0); STAGE_B(0, 3, 0);
    STAGE_B(1, 0, 1); STAGE_B(1, 1, 1); STAGE_B(1, 2, 1); STAGE_B(1, 3, 1);
    STAGE_A(1, 0, 1); STAGE_A(1, 2, 1);
    asm volatile("s_waitcnt vmcnt(6)" ::: "memory");
    __builtin_amdgcn_sched_barrier(0);
    __builtin_amdgcn_s_barrier();
    __builtin_amdgcn_sched_barrier(0);

#define PRE_BAR()                                                   \
    __builtin_amdgcn_sched_barrier(0);                              \
    __builtin_amdgcn_s_barrier();                                   \
    asm volatile("s_waitcnt lgkmcnt(0)" ::: "memory");              \
    __builtin_amdgcn_sched_barrier(0);

#define POST_BAR()                                                  \
    __builtin_amdgcn_sched_barrier(0);                              \
    __builtin_amdgcn_s_barrier();                                   \
    __builtin_amdgcn_sched_barrier(0);

// 24 mfma32, round-robin over 4 accumulators (dep distance 4):
// products hh, hl, lh; kk0 then kk1 inside each product.
#define CLUSTER(RA, RB, A0H0, A0H1, A0L0, A0L1, A1H0, A1H1, A1L0, A1L1) \
    __builtin_amdgcn_s_setprio(1);                                  \
    acc[RA][0] = mfma32(A0H0, b0h0, acc[RA][0]);                    \
    acc[RA][1] = mfma32(A0H0, b1h0, acc[RA][1]);                    \
    acc[RB][0] = mfma32(A1H0, b0h0, acc[RB][0]);                    \
    acc[RB][1] = mfma32(A1H0, b1h0, acc[RB][1]);                    \
    acc[RA][0] = mfma32(A0H1, b0h1, acc[RA][0]);                    \
    acc[RA][1] = mfma32(A0H1, b1h1, acc[RA][1]);                    \
    acc[RB][0] = mfma32(A1H1, b0h1, acc[RB][0]);                    \
    acc[RB][1] = mfma32(A1H1, b1h1, acc[RB][1]);                    \
    acc[RA][0] = mfma32(A0H0, b0l0, acc[RA][0]);                    \
    acc[RA][1] = mfma32(A0H0, b1l0, acc[RA][1]);                    \
    acc[RB][0] = mfma32(A1H0, b0l0, acc[RB][0]);                    \
    acc[RB][1] = mfma32(A1H0, b1l0, acc[RB][1]);                    \
    acc[RA][0] = mfma32(A0H1, b0l1, acc[RA][0]);                    \
    acc[RA][1] = mfma32(A0H1, b1l1, acc[RA][1]);                    \
    acc[RB][0] = mfma32(A1H1, b0l1, acc[RB][0]);                    \
    acc[RB][1] = mfma32(A1H1, b1l1, acc[RB][1]);                    \
    acc[RA][0] = mfma32(A0L0, b0h0, acc[RA][0]);                    \
    acc[RA][1] = mfma32(A0L0, b1h0, acc[RA][1]);                    \
    acc[RB][0] = mfma32(A1L0, b0h0, acc[RB][0]);                    \
    acc[RB][1] = mfma32(A1L0, b1h0, acc[RB][1]);                    \
    acc[RA][0] = mfma32(A0L1, b0h1, acc[RA][0]);                    \
    acc[RA][1] = mfma32(A0L1, b1h1, acc[RA][1]);                    \
    acc[RB][0] = mfma32(A1L1, b0h1, acc[RB][0]);                    \
    acc[RB][1] = mfma32(A1L1, b1h1, acc[RB][1]);                    \
    __builtin_amdgcn_s_setprio(0);

    #pragma unroll 2
    for (int t = 0; t < NT; ++t) {
        const unsigned bo = (unsigned)((t & 1) << 16);
        const unsigned aT = aB + bo;
        const unsigned bT = bB + bo;
        const int cc = t & 1;

        // B frags: b{nf}{h/l}{kk}, offset = nf*4096 + kk*2048 + part*1024
        bf16x8 b0h0, b0h1, b0l0, b0l1, b1h0, b1h1, b1l0, b1l1;
        bf16x8 x0h0, x0h1, x0l0, x0l1, x1h0, x1h1, x1l0, x1l1;

        // ---- phase 0: read B(all) + A(mf0,1); stage A(t+1) calls 1,3 ----
        b0h0 = dsr128(bT + 0u);    b0l0 = dsr128(bT + 1024u);
        b0h1 = dsr128(bT + 2048u); b0l1 = dsr128(bT + 3072u);
        b1h0 = dsr128(bT + 4096u); b1l0 = dsr128(bT + 5120u);
        b1h1 = dsr128(bT + 6144u); b1l1 = dsr128(bT + 7168u);
        x0h0 = dsr128(aT + 0u);    x0l0 = dsr128(aT + 1024u);
        x0h1 = dsr128(aT + 2048u); x0l1 = dsr128(aT + 3072u);
        x1h0 = dsr128(aT + 4096u); x1l0 = dsr128(aT + 5120u);
        x1h1 = dsr128(aT + 6144u); x1l1 = dsr128(aT + 7168u);
        if (t < NT - 1) { STAGE_A(cc ^ 1, 1, t + 1); STAGE_A(cc ^ 1, 3, t + 1); }
        PRE_BAR();
        CLUSTER(0, 1, x0h0, x0h1, x0l0, x0l1, x1h0, x1h1, x1l0, x1l1);
        POST_BAR();

        // ---- phase 1: read A(mf2,3); stage B(t+2) + A(t+2) calls 0,2 ----
        x0h0 = dsr128(aT + 8192u);  x0l0 = dsr128(aT + 9216u);
        x0h1 = dsr128(aT + 10240u); x0l1 = dsr128(aT + 11264u);
        x1h0 = dsr128(aT + 12288u); x1l0 = dsr128(aT + 13312u);
        x1h1 = dsr128(aT + 14336u); x1l1 = dsr128(aT + 15360u);
        if (t < NT - 2) {
            STAGE_B(cc, 0, t + 2); STAGE_B(cc, 1, t + 2);
            STAGE_B(cc, 2, t + 2); STAGE_B(cc, 3, t + 2);
            STAGE_A(cc, 0, t + 2); STAGE_A(cc, 2, t + 2);
        }
        PRE_BAR();
        CLUSTER(2, 3, x0h0, x0h1, x0l0, x0l1, x1h0, x1h1, x1l0, x1l1);
        __builtin_amdgcn_sched_barrier(0);
        if (t < NT - 2) {
            asm volatile("s_waitcnt vmcnt(6)" ::: "memory");
        } else if (t == NT - 2) {
            asm volatile("s_waitcnt vmcnt(0)" ::: "memory");
        }
        POST_BAR();
    }

#undef PRE_BAR
#undef POST_BAR
#undef CLUSTER

    // ---- fused LSTM epilogue (32x32 C layout: col=lane&31,
    //      row=(r&3)+8*(r>>2)+4*(lane>>5)) ----
    const int lb = lane & ~3;
    const int64_t OFF_H = (int64_t)B_DIM * H_DIM;
    const int64_t OFF_C = (int64_t)2 * B_DIM * H_DIM;
    #pragma unroll
    for (int mf = 0; mf < 4; mf++)
        #pragma unroll
        for (int nf = 0; nf < 2; nf++) {
            int col = n0 + wc + nf * 32 + l31;  // n' = 4h+g
            int g = lane & 3;
            int h = col >> 2;
            float bb = bias[col];
            int rowbase = m0 + wr + mf * 32 + 4 * lh;
            #pragma unroll
            for (int r = 0; r < 16; r++) {
                int row = rowbase + (r & 3) + 8 * (r >> 2);
                float v = acc[mf][nf][r] + bb;
                float a = (g == 2) ? tanhf(v) : 1.0f / (1.0f + expf(-v));
                float fg = __shfl(a, lb + 0, 64);
                float ig = __shfl(a, lb + 1, 64);
                float ct = __shfl(a, lb + 2, 64);
                float og = __shfl(a, lb + 3, 64);
                int64_t o = (int64_t)row * H_DIM + h;
                float cn = fg * cell[o] + ig * ct;
                float hn = og * tanhf(cn);
                int role = lane & 3;
                if (role == 0) {
                    out0[OFF_C + o] = cn;
                } else if (role == 1) {
                    out0[OFF_H + o] = hn;
                } else if (role == 2) {
                    hhi[o] = f2bf(hn);
                } else {
                    unsigned short t2 = f2bf(hn);
                    hlo[o] = f2bf(hn - bf2f(t2));
                }
            }
        }
}

// ---------------------------------------------------------------------------
// LOGITS GEMM: bf16x3, 128x128 tile, BK=32, 4 waves (m97 structure).
// ---------------------------------------------------------------------------
__global__ __launch_bounds__(256, 2) void k_gemm128(
    const unsigned short* __restrict__ Ahi, const unsigned short* __restrict__ Alo,
    const unsigned short* __restrict__ Bhi, const unsigned short* __restrict__ Blo,
    int K, int Ncols,
    const float* __restrict__ bias,
    float* __restrict__ out0) {
    __shared__ char smem[32768];

    const int tid  = threadIdx.x;
    const int lane = tid & 63;
    const int w    = tid >> 6;
    const int wr   = (w >> 1) * 64;
    const int wc   = (w & 1) * 64;
    const int m0   = blockIdx.y * 128;
    const int n0   = blockIdx.x * 128;

    f32x4 acc[4][4];
    #pragma unroll
    for (int i = 0; i < 4; i++)
        #pragma unroll
        for (int j = 0; j < 4; j++) acc[i][j] = (f32x4){0.f, 0.f, 0.f, 0.f};

    const int sr = tid >> 3;
    const int s2 = (tid & 7) ^ (sr & 7);
    const unsigned short* Asrc =
        ((s2 < 4) ? Ahi : Alo) + (int64_t)(m0 + sr) * K + (s2 & 3) * 8;
    const unsigned short* Bsrc =
        ((s2 < 4) ? Bhi : Blo) + (int64_t)(n0 + sr) * K + (s2 & 3) * 8;

    const int q  = lane >> 4;
    const int fr = lane & 15;
    const int sw = lane & 7;
    const int hiSlot = (q ^ sw) << 4;
    const int loSlot = ((q + 4) ^ sw) << 4;

    for (int kt = 0; kt < K; kt += 32) {
        __syncthreads();
        #pragma unroll
        for (int i = 0; i < 4; i++) {
            gload_lds16(Asrc + (int64_t)i * 32 * K + kt, smem + i * 4096 + w * 1024);
            gload_lds16(Bsrc + (int64_t)i * 32 * K + kt, smem + 16384 + i * 4096 + w * 1024);
        }
        __syncthreads();

        bf16x8 ah[4], al[4], bh[4], bl[4];
        #pragma unroll
        for (int mi = 0; mi < 4; mi++) {
            const char* rp = smem + (wr + mi * 16 + fr) * 128;
            ah[mi] = *(const bf16x8*)(rp + hiSlot);
            al[mi] = *(const bf16x8*)(rp + loSlot);
        }
        #pragma unroll
        for (int ni = 0; ni < 4; ni++) {
            const char* rp = smem + 16384 + (wc + ni * 16 + fr) * 128;
            bh[ni] = *(const bf16x8*)(rp + hiSlot);
            bl[ni] = *(const bf16x8*)(rp + loSlot);
        }
        #pragma unroll
        for (int mi = 0; mi < 4; mi++)
            #pragma unroll
            for (int ni = 0; ni < 4; ni++) {
                acc[mi][ni] = mfma16(ah[mi], bh[ni], acc[mi][ni]);
                acc[mi][ni] = mfma16(ah[mi], bl[ni], acc[mi][ni]);
                acc[mi][ni] = mfma16(al[mi], bh[ni], acc[mi][ni]);
            }
    }

    #pragma unroll
    for (int mi = 0; mi < 4; mi++)
        #pragma unroll
        for (int ni = 0; ni < 4; ni++) {
            int col = n0 + wc + ni * 16 + fr;
            int rowb = m0 + wr + mi * 16 + q * 4;
            float bb = bias[col];
            #pragma unroll
            for (int j = 0; j < 4; j++)
                out0[(int64_t)(rowb + j) * Ncols + col] = acc[mi][ni][j] + bb;
        }
}

// ---------------------------------------------------------------------------
// Row-wise log_softmax over [8192][1024]: one block per row.
// ---------------------------------------------------------------------------
__global__ __launch_bounds__(256) void k_logsoftmax(
    const float* __restrict__ logits, float* __restrict__ out) {
    const int row = blockIdx.x;
    const int t = threadIdx.x;
    const float* x = logits + (int64_t)row * 1024;
    float4 v = *(const float4*)(x + t * 4);

    float m = fmaxf(fmaxf(v.x, v.y), fmaxf(v.z, v.w));
    #pragma unroll
    for (int off = 1; off < 64; off <<= 1) m = fmaxf(m, __shfl_xor(m, off, 64));
    __shared__ float sm[4];
    __shared__ float ssum[4];
    int ln = t & 63, wv = t >> 6;
    if (ln == 0) sm[wv] = m;
    __syncthreads();
    m = fmaxf(fmaxf(sm[0], sm[1]), fmaxf(sm[2], sm[3]));

    float s = expf(v.x - m) + expf(v.y - m) + expf(v.z - m) + expf(v.w - m);
    #pragma unroll
    for (int off = 1; off < 64; off <<= 1) s += __shfl_xor(s, off, 64);
    if (ln == 0) ssum[wv] = s;
    __syncthreads();
    s = ssum[0] + ssum[1] + ssum[2] + ssum[3];

    float lse = m + logf(s);
    float4 o;
    o.x = v.x - lse; o.y = v.y - lse; o.z = v.z - lse; o.w = v.w - lse;
    *(float4*)(out + (int64_t)row * 1024 + t * 4) = o;
}

// ---------------------------------------------------------------------------
extern "C" void kernel_launch(void* const* d_in, const int* in_sizes, int n_in,
                              void* d_out, int out_size, void* d_ws, size_t ws_size,
                              hipStream_t stream) {
    const float* input  = (const float*)d_in[0];
    const float* hidden = (const float*)d_in[1];
    const float* cell   = (const float*)d_in[2];
    const float* W_f = (const float*)d_in[3];
    const float* U_f = (const float*)d_in[4];
    const float* b_f = (const float*)d_in[5];
    const float* W_i = (const float*)d_in[6];
    const float* U_i = (const float*)d_in[7];
    const float* b_i = (const float*)d_in[8];
    const float* W_c = (const float*)d_in[9];
    const float* U_c = (const float*)d_in[10];
    const float* b_c = (const float*)d_in[11];
    const float* W_o = (const float*)d_in[12];
    const float* U_o = (const float*)d_in[13];
    const float* b_o = (const float*)d_in[14];
    const float* W_h = (const float*)d_in[15];
    const float* b_h = (const float*)d_in[16];
    float* out = (float*)d_out;

    char* ws = (char*)d_ws;
    char*           Apan = ws;                                  // 64 MB
    char*           Bpan = ws + 67108864;                       // 32 MB
    unsigned short* hhi  = (unsigned short*)(ws + 100663296);   // 16 MB
    unsigned short* hlo  = (unsigned short*)(ws + 117440512);   // 16 MB
    unsigned short* whhi = (unsigned short*)(ws + 134217728);   // 2 MB
    unsigned short* whlo = (unsigned short*)(ws + 136314880);   // 2 MB
    float*          bias4 = (float*)(ws + 138412032);           // 16 KB
    float*          logits = (float*)(ws);                      // aliases Apan
    if (ws_size < (size_t)138428416) return;

    hipFuncSetAttribute((const void*)k_gate_gemm256,
                        hipFuncAttributeMaxDynamicSharedMemorySize, 131072);

    k_pack_x<<<2048, 256, 0, stream>>>(input, hidden, Apan);

    const float* Warr[8] = {W_f, W_i, W_c, W_o, U_f, U_i, U_c, U_o};
    for (int a = 0; a < 8; a++)
        k_trans_split_pan<<<dim3(16, 16), 256, 0, stream>>>(
            Warr[a], Bpan, a & 3, (a >> 2) * 1024);
    k_trans_split<<<dim3(16, 16), 256, 0, stream>>>(W_h, whhi, whlo);
    k_pack_bias<<<16, 256, 0, stream>>>(b_f, b_i, b_c, b_o, bias4);

    // gates GEMM + fused LSTM epilogue: M=8192, N'=4096, K=2048, 512 blocks
    k_gate_gemm256<<<512, 512, 131072, stream>>>(
        Apan, Bpan, bias4, cell, out, hhi, hlo);

    // logits GEMM: M=8192, N=1024, K=1024
    k_gemm128<<<dim3(8, 64), 256, 0, stream>>>(
        hhi, hlo, whhi, whlo, 1024, 1024, b_h, logits);

    k_logsoftmax<<<8192, 256, 0, stream>>>(logits, out);
}